// Round 2
// baseline (853.581 us; speedup 1.0000x reference)
//
#include <hip/hip_runtime.h>

typedef unsigned short u16;
typedef unsigned int u32;
typedef __attribute__((ext_vector_type(8))) __bf16 bf16x8;
typedef __attribute__((ext_vector_type(4))) float f32x4;
typedef __attribute__((ext_vector_type(16))) float f32x16;

#define CLEN 1664
#define SEQL 4992
#define NHEADS 16
#define HD 128
#define HID 2048
#define KVD 512
#define SCALE 0.08838834764831845f

__device__ __forceinline__ u16 f2bf(float f) {
  union { float f; u32 u; } v; v.f = f;
  u32 u = v.u;
  return (u16)((u + 0x7FFFu + ((u >> 16) & 1u)) >> 16);
}
__device__ __forceinline__ float bf2f(u16 h) {
  union { u32 u; float f; } v; v.u = (u32)h << 16;
  return v.f;
}
__device__ __forceinline__ f32x4 mfma16(bf16x8 a, bf16x8 b, f32x4 c) {
  return __builtin_amdgcn_mfma_f32_16x16x32_bf16(a, b, c, 0, 0, 0);
}
__device__ __forceinline__ f32x16 mfma32(bf16x8 a, bf16x8 b, f32x16 c) {
  return __builtin_amdgcn_mfma_f32_32x32x16_bf16(a, b, c, 0, 0, 0);
}
__device__ __forceinline__ u32 cvtpk(float lo, float hi) {
  u32 r;
  asm("v_cvt_pk_bf16_f32 %0, %1, %2" : "=v"(r) : "v"(lo), "v"(hi));
  return r;
}
__device__ __forceinline__ void gload_lds16(const u16* g, u16* l) {
  __builtin_amdgcn_global_load_lds((const __attribute__((address_space(1))) void*)g,
                                   (__attribute__((address_space(3))) void*)l, 16, 0, 0);
}

// ---------------- f32 -> bf16 convert ----------------
__global__ void cvt_kernel(const float* __restrict__ src, u16* __restrict__ dst, int n) {
  int i = (blockIdx.x * blockDim.x + threadIdx.x) * 4;
  if (i >= n) return;
  float4 v = *(const float4*)(src + i);
  uint2 p;
  p.x = (u32)f2bf(v.x) | ((u32)f2bf(v.y) << 16);
  p.y = (u32)f2bf(v.z) | ((u32)f2bf(v.w) << 16);
  *(uint2*)(dst + i) = p;
}

// ---------------- RoPE (bf16 src -> bf16 dst), 8 elems/thread ----------------
// mode 0: pid = s % CLEN ; mode 1: pid = s ; mode 2: pid = CLEN-1
__global__ void rope_kernel(const u16* __restrict__ src, const float* __restrict__ cost,
                            const float* __restrict__ sint, u16* __restrict__ dst,
                            int nrows, int row0, int rowlen, int mode) {
  int idx = blockIdx.x * blockDim.x + threadIdx.x;
  int ng = rowlen >> 3;
  if (idx >= nrows * ng) return;
  int r = idx / ng;
  int col = (idx - r * ng) * 8;
  int s = row0 + r;
  int pid = (mode == 0) ? (s % CLEN) : (mode == 1 ? s : (CLEN - 1));
  int dh = col & 127;
  const bool hihalf = dh >= 64;
  const u16* rowp = src + (size_t)s * rowlen;
  union { uint4 u; u16 s[8]; } X, P, O;
  X.u = *(const uint4*)(rowp + col);
  P.u = *(const uint4*)(rowp + col + (hihalf ? -64 : 64));
  const float* cp = cost + pid * 128 + dh;
  const float* sp = sint + pid * 128 + dh;
#pragma unroll
  for (int j = 0; j < 8; ++j) {
    float xf = bf2f(X.s[j]);
    float pf = bf2f(P.s[j]);
    float v = xf * cp[j] + (hihalf ? pf : -pf) * sp[j];
    O.s[j] = f2bf(v);
  }
  *(uint4*)(dst + (size_t)r * rowlen + col) = O.u;
}

// ---------------- GEMM: C[M][N] = A[M][K] * B[N][K]^T (bf16 in, f32 acc) ------
// EPI 0: f32 C ; EPI 1: bf16 C ; EPI 2: bf16 scatter C^T (vT layout [N][M])
template <int EPI>
__global__ __launch_bounds__(256) void gemm_bt(const u16* __restrict__ A, const u16* __restrict__ B,
                                               float* __restrict__ Cf, u16* __restrict__ Cb,
                                               int M, int N, int K) {
  __shared__ __align__(16) u16 Al[128 * 64];
  __shared__ __align__(16) u16 Bl[128 * 64];
  const int t = threadIdx.x;
  const int lane = t & 63, wid = t >> 6;
  const int g = lane >> 4, c = lane & 15;
  const int wr = wid >> 1, wc = wid & 1;
  const int m0 = blockIdx.x * 128, n0 = blockIdx.y * 128;

  f32x4 acc[4][4];
#pragma unroll
  for (int m = 0; m < 4; ++m)
#pragma unroll
    for (int n = 0; n < 4; ++n) acc[m][n] = (f32x4){0.f, 0.f, 0.f, 0.f};

  const int srow = t >> 3;        // 0..31
  const int scol = (t & 7) * 8;   // element col in [0,64)
  for (int k0 = 0; k0 < K; k0 += 64) {
    __syncthreads();
#pragma unroll
    for (int i = 0; i < 4; ++i) {
      const int r = i * 32 + srow;
      // LDS layout is linear in thread id: byte off = i*4096 + t*16
      gload_lds16(A + (size_t)(m0 + r) * K + k0 + scol, Al + i * 2048 + wid * 512);
      gload_lds16(B + (size_t)(n0 + r) * K + k0 + scol, Bl + i * 2048 + wid * 512);
    }
    __syncthreads();
#pragma unroll
    for (int kk = 0; kk < 2; ++kk) {
      bf16x8 af[4], bfr[4];
#pragma unroll
      for (int m = 0; m < 4; ++m)
        af[m] = *(const bf16x8*)(Al + (wr * 64 + m * 16 + c) * 64 + kk * 32 + g * 8);
#pragma unroll
      for (int n = 0; n < 4; ++n)
        bfr[n] = *(const bf16x8*)(Bl + (wc * 64 + n * 16 + c) * 64 + kk * 32 + g * 8);
#pragma unroll
      for (int m = 0; m < 4; ++m)
#pragma unroll
        for (int n = 0; n < 4; ++n)
          acc[m][n] = mfma16(af[m], bfr[n], acc[m][n]);
    }
  }
#pragma unroll
  for (int m = 0; m < 4; ++m)
#pragma unroll
    for (int n = 0; n < 4; ++n)
#pragma unroll
      for (int j = 0; j < 4; ++j) {
        const int row = m0 + wr * 64 + m * 16 + 4 * g + j;
        const int col = n0 + wc * 64 + n * 16 + c;
        const float v = acc[m][n][j];
        if (EPI == 0) Cf[(size_t)row * N + col] = v;
        else if (EPI == 1) Cb[(size_t)row * N + col] = f2bf(v);
        else Cb[(size_t)col * M + row] = f2bf(v);
      }
}

// ---------------- fused chunk attention, swapped-QK 32x32 structure ----------
// grid: (13, 3, 16), block 256 = 4 waves x 32 q-rows. KV tile = 64.
__global__ __launch_bounds__(256) void attn_kernel(
    const u16* __restrict__ qa, const u16* __restrict__ qb, const u16* __restrict__ qf,
    const u16* __restrict__ kbf, const u16* __restrict__ vT, u16* __restrict__ aout) {
  __shared__ __align__(16) u16 Klds[64 * 128];  // [kv][d], b128 granule cb ^= (row&7)
  __shared__ __align__(16) u16 Vlds[128 * 64];  // [d][kv], b128 granule cb ^= (row&7)
  __shared__ float albuf[4][32];

  const int qt = blockIdx.x, chunk = blockIdx.y, head = blockIdx.z;
  const int t = threadIdx.x, wid = t >> 6, lane = t & 63;
  const int ql = lane & 31;
  const int hi = lane >> 5;
  const int kvh = head >> 2;

  const int qcb = qt * 128 + wid * 32;  // wave q base within chunk
  const int qpos = qcb + ql;            // this lane's q position within chunk

  float m_r = 0.f, l_r = 0.f;
  f32x16 oacc[4];
#pragma unroll
  for (int db = 0; db < 4; ++db)
#pragma unroll
    for (int r = 0; r < 16; ++r) oacc[db][r] = 0.f;

  const int ksr = t >> 4, ksc = t & 15;  // K staging: row ksr+16i, granule ksc
  const int vsr = t >> 3, vsc = t & 7;   // V staging: row vsr+32i, granule vsc

  for (int seg = 0; seg <= chunk; ++seg) {
    const bool causal = (seg == chunk);
    const u16* qp; int qoff;
    if (seg == chunk)          { qp = qa; qoff = 0; }
    else if (seg == chunk - 1) { qp = qb; qoff = CLEN; }
    else                       { qp = qf; qoff = 2 * CLEN; }
    const int kvbase = seg * CLEN;

    // Q fragments: lane holds Q row (qpos), elements d = 16*ck + 8*hi + i
    bf16x8 aq[8];
    {
      const u16* qrow = qp + (size_t)(chunk * CLEN + qpos - qoff) * HID + head * HD + hi * 8;
#pragma unroll
      for (int ck = 0; ck < 8; ++ck) aq[ck] = *(const bf16x8*)(qrow + ck * 16);
    }

    const int ntiles = causal ? (qt * 2 + 2) : (CLEN / 64);

    for (int kt = 0; kt < ntiles; ++kt) {
      const int kv0 = kt * 64;
      __syncthreads();
#pragma unroll
      for (int i = 0; i < 4; ++i) {
        const int r = ksr + 16 * i;
        bf16x8 val = *(const bf16x8*)(kbf + (size_t)(kvbase + kv0 + r) * KVD + kvh * HD + ksc * 8);
        *(bf16x8*)(Klds + r * 128 + ((ksc ^ (r & 7)) * 8)) = val;
      }
#pragma unroll
      for (int i = 0; i < 4; ++i) {
        const int r = vsr + 32 * i;
        bf16x8 val = *(const bf16x8*)(vT + (size_t)(kvh * HD + r) * SEQL + kvbase + kv0 + vsc * 8);
        *(bf16x8*)(Vlds + r * 64 + ((vsc ^ (r & 7)) * 8)) = val;
      }
      __syncthreads();

#pragma unroll
      for (int s = 0; s < 2; ++s) {
        if (!(causal && kv0 + 32 * s > qcb + 31)) {
          // ---- QK^T (swapped): S^T[kv][q], lane owns q=ql, 16 kv rows ----
          f32x16 sacc;
#pragma unroll
          for (int r = 0; r < 16; ++r) sacc[r] = 0.f;
          const int kr = 32 * s + ql;
          const int r7 = lane & 7;
#pragma unroll
          for (int ck = 0; ck < 8; ++ck) {
            bf16x8 kb = *(const bf16x8*)(Klds + kr * 128 + (((2 * ck + hi) ^ r7) * 8));
            sacc = mfma32(kb, aq[ck], sacc);
          }
          // ---- softmax (lane-local; kv row of reg r = (r&3)+8*(r>>2)+4*hi) ----
          float e[16];
          float mt = -1e30f;
#pragma unroll
          for (int r = 0; r < 16; ++r) {
            const int kvp = kv0 + 32 * s + (r & 3) + 8 * (r >> 2) + 4 * hi;
            float ev = sacc[r] * SCALE;
            if (causal && kvp > qpos) ev = -1e30f;
            e[r] = ev;
            mt = fmaxf(mt, ev);
          }
          mt = fmaxf(mt, __shfl_xor(mt, 32));
          if (!__all(mt <= m_r + 8.f)) {  // rare rescale path (defer-max)
            const float mnew = fmaxf(m_r, mt);
            const float al = __expf(m_r - mnew);
            m_r = mnew; l_r *= al;
            albuf[wid][ql] = al;
            asm volatile("s_waitcnt lgkmcnt(0)" ::: "memory");
#pragma unroll
            for (int r = 0; r < 16; ++r) {
              const float alr = albuf[wid][(r & 3) + 8 * (r >> 2) + 4 * hi];
#pragma unroll
              for (int db = 0; db < 4; ++db) oacc[db][r] *= alr;
            }
          }
          float rs = 0.f;
#pragma unroll
          for (int r = 0; r < 16; ++r) { e[r] = __expf(e[r] - m_r); rs += e[r]; }
          rs += __shfl_xor(rs, 32);
          l_r += rs;
          // ---- pack P to bf16 (in-register, no cross-lane needed) ----
          u32 w[8];
#pragma unroll
          for (int j = 0; j < 8; ++j) w[j] = cvtpk(e[2 * j], e[2 * j + 1]);
          // ---- PV: O[q][d] += P V ; k-slot i<->kv permutation folded into V reads
#pragma unroll
          for (int ks = 0; ks < 2; ++ks) {
            union { uint4 u; bf16x8 v; } pa;
            pa.u.x = w[4 * ks]; pa.u.y = w[4 * ks + 1];
            pa.u.z = w[4 * ks + 2]; pa.u.w = w[4 * ks + 3];
            const int g4a = 8 * s + 4 * ks + hi;   // b64 granule (4 kv) in Vlds row
            const int sw = (lane & 7) << 1;
#pragma unroll
            for (int db = 0; db < 4; ++db) {
              const int vrow = 32 * db + ql;
              const uint2 v0 = *(const uint2*)(Vlds + vrow * 64 + ((g4a ^ sw) * 4));
              const uint2 v1 = *(const uint2*)(Vlds + vrow * 64 + (((g4a + 2) ^ sw) * 4));
              union { uint4 u; bf16x8 v; } bv;
              bv.u.x = v0.x; bv.u.y = v0.y; bv.u.z = v1.x; bv.u.w = v1.y;
              oacc[db] = mfma32(pa.v, bv.v, oacc[db]);
            }
          }
        }
      }
    }
  }
  // ---- epilogue: broadcast 1/l per kv-row via LDS, store bf16 ----
  const float linv = 1.0f / l_r;
  albuf[wid][ql] = linv;
  asm volatile("s_waitcnt lgkmcnt(0)" ::: "memory");
#pragma unroll
  for (int r = 0; r < 16; ++r) {
    const int rrow = (r & 3) + 8 * (r >> 2) + 4 * hi;
    const float li = albuf[wid][rrow];
    const size_t grow = (size_t)(chunk * CLEN + qcb + rrow);
#pragma unroll
    for (int db = 0; db < 4; ++db)
      aout[grow * HID + head * HD + db * 32 + ql] = f2bf(oacc[db][r] * li);
  }
}

extern "C" void kernel_launch(void* const* d_in, const int* in_sizes, int n_in,
                              void* d_out, int out_size, void* d_ws, size_t ws_size,
                              hipStream_t stream) {
  (void)in_sizes; (void)n_in; (void)out_size; (void)ws_size;
  const float* hidden = (const float*)d_in[0];
  const float* q_cos = (const float*)d_in[2];
  const float* q_sin = (const float*)d_in[3];
  const float* qc_cos = (const float*)d_in[4];
  const float* qc_sin = (const float*)d_in[5];
  const float* k_cos = (const float*)d_in[6];
  const float* k_sin = (const float*)d_in[7];
  const float* Wq = (const float*)d_in[8];
  const float* Wk = (const float*)d_in[9];
  const float* Wv = (const float*)d_in[10];
  const float* Wo = (const float*)d_in[11];
  float* out = (float*)d_out;

  char* ws = (char*)d_ws;
  size_t off = 0;
  auto alloc = [&](size_t bytes) { char* p = ws + off; off += (bytes + 255) & ~(size_t)255; return p; };
  u16* h_bf  = (u16*)alloc((size_t)SEQL * HID * 2);
  u16* Wq_bf = (u16*)alloc((size_t)HID * HID * 2);
  u16* Wk_bf = (u16*)alloc((size_t)KVD * HID * 2);
  u16* Wv_bf = (u16*)alloc((size_t)KVD * HID * 2);
  u16* Wo_bf = (u16*)alloc((size_t)HID * HID * 2);
  u16* q_tmp = (u16*)alloc((size_t)SEQL * HID * 2);
  u16* k_tmp = (u16*)alloc((size_t)SEQL * KVD * 2);
  u16* qa   = (u16*)alloc((size_t)SEQL * HID * 2);
  u16* qb   = (u16*)alloc((size_t)2 * CLEN * HID * 2);
  u16* qf   = (u16*)alloc((size_t)CLEN * HID * 2);
  u16* k_bf = (u16*)alloc((size_t)SEQL * KVD * 2);
  u16* vT   = (u16*)alloc((size_t)KVD * SEQL * 2);
  u16* amrg = (u16*)alloc((size_t)SEQL * HID * 2);

  auto cvt = [&](const float* s, u16* d, int n) {
    cvt_kernel<<<dim3((n / 4 + 255) / 256), dim3(256), 0, stream>>>(s, d, n);
  };
  cvt(hidden, h_bf, SEQL * HID);
  cvt(Wq, Wq_bf, HID * HID);
  cvt(Wk, Wk_bf, KVD * HID);
  cvt(Wv, Wv_bf, KVD * HID);
  cvt(Wo, Wo_bf, HID * HID);

  gemm_bt<1><<<dim3(SEQL / 128, HID / 128), 256, 0, stream>>>(h_bf, Wq_bf, nullptr, q_tmp, SEQL, HID, HID);
  gemm_bt<1><<<dim3(SEQL / 128, KVD / 128), 256, 0, stream>>>(h_bf, Wk_bf, nullptr, k_tmp, SEQL, KVD, HID);
  gemm_bt<2><<<dim3(SEQL / 128, KVD / 128), 256, 0, stream>>>(h_bf, Wv_bf, nullptr, vT, SEQL, KVD, HID);

  auto rope = [&](const u16* s, const float* ct, const float* st, u16* d,
                  int nrows, int row0, int rowlen, int mode) {
    int total = nrows * (rowlen / 8);
    rope_kernel<<<dim3((total + 255) / 256), dim3(256), 0, stream>>>(s, ct, st, d, nrows, row0, rowlen, mode);
  };
  rope(q_tmp, q_cos, q_sin, qa, SEQL, 0, HID, 0);
  rope(q_tmp, qc_cos, qc_sin, qb, 2 * CLEN, CLEN, HID, 0);
  rope(q_tmp, qc_cos, qc_sin, qf, CLEN, 2 * CLEN, HID, 2);
  rope(k_tmp, k_cos, k_sin, k_bf, SEQL, 0, KVD, 1);

  attn_kernel<<<dim3(CLEN / 128, 3, NHEADS), 256, 0, stream>>>(qa, qb, qf, k_bf, vT, amrg);

  gemm_bt<0><<<dim3(SEQL / 128, HID / 128), 256, 0, stream>>>(amrg, Wo_bf, out, nullptr, SEQL, HID, HID);
}

// Round 4
// 579.345 us; speedup vs baseline: 1.4734x; 1.4734x over previous
//
#include <hip/hip_runtime.h>

typedef unsigned short u16;
typedef unsigned int u32;
typedef __attribute__((ext_vector_type(8))) __bf16 bf16x8;
typedef __attribute__((ext_vector_type(4))) float f32x4;
typedef __attribute__((ext_vector_type(16))) float f32x16;

#define CLEN 1664
#define SEQL 4992
#define NHEADS 16
#define HD 128
#define HID 2048
#define KVD 512
#define SCALE 0.08838834764831845f

__device__ __forceinline__ u16 f2bf(float f) {
  union { float f; u32 u; } v; v.f = f;
  u32 u = v.u;
  return (u16)((u + 0x7FFFu + ((u >> 16) & 1u)) >> 16);
}
__device__ __forceinline__ float bf2f(u16 h) {
  union { u32 u; float f; } v; v.u = (u32)h << 16;
  return v.f;
}
__device__ __forceinline__ f32x4 mfma16(bf16x8 a, bf16x8 b, f32x4 c) {
  return __builtin_amdgcn_mfma_f32_16x16x32_bf16(a, b, c, 0, 0, 0);
}
__device__ __forceinline__ f32x16 mfma32(bf16x8 a, bf16x8 b, f32x16 c) {
  return __builtin_amdgcn_mfma_f32_32x32x16_bf16(a, b, c, 0, 0, 0);
}
__device__ __forceinline__ u32 cvtpk(float lo, float hi) {
  u32 r;
  asm("v_cvt_pk_bf16_f32 %0, %1, %2" : "=v"(r) : "v"(lo), "v"(hi));
  return r;
}
__device__ __forceinline__ void gload_lds16(const u16* g, u16* l) {
  __builtin_amdgcn_global_load_lds((const __attribute__((address_space(1))) void*)g,
                                   (__attribute__((address_space(3))) void*)l, 16, 0, 0);
}

// ---------------- fused f32 -> bf16 convert (5 regions, 1 launch) ----------
#define CVT_Q0 2555904   // hidden  (10223616/4)
#define CVT_Q1 1048576   // Wq
#define CVT_Q2 262144    // Wk
#define CVT_Q3 262144    // Wv
#define CVT_Q4 1048576   // Wo
__device__ __forceinline__ void cvt4(const float* s, u16* d, int q) {
  float4 v = *(const float4*)(s + (size_t)q * 4);
  uint2 p;
  p.x = (u32)f2bf(v.x) | ((u32)f2bf(v.y) << 16);
  p.y = (u32)f2bf(v.z) | ((u32)f2bf(v.w) << 16);
  *(uint2*)(d + (size_t)q * 4) = p;
}
__global__ void cvt_all_kernel(const float* __restrict__ hidden, const float* __restrict__ Wq,
                               const float* __restrict__ Wk, const float* __restrict__ Wv,
                               const float* __restrict__ Wo, u16* __restrict__ h_bf,
                               u16* __restrict__ Wqkv, u16* __restrict__ Wo_bf) {
  int q = blockIdx.x * blockDim.x + threadIdx.x;
  if (q < CVT_Q0) { cvt4(hidden, h_bf, q); return; }
  q -= CVT_Q0;
  if (q < CVT_Q1) { cvt4(Wq, Wqkv, q); return; }
  q -= CVT_Q1;
  if (q < CVT_Q2) { cvt4(Wk, Wqkv + 2048 * 2048, q); return; }
  q -= CVT_Q2;
  if (q < CVT_Q3) { cvt4(Wv, Wqkv + 2560 * 2048, q); return; }
  q -= CVT_Q3;
  if (q < CVT_Q4) cvt4(Wo, Wo_bf, q);
}

// ---------------- fused RoPE (4 regions, 1 launch) --------------------------
#define RP_N0 1277952  // qa : 4992*256
#define RP_N1 851968   // qb : 3328*256
#define RP_N2 425984   // qf : 1664*256
#define RP_N3 319488   // k  : 4992*64
__device__ __forceinline__ void rope8(const u16* __restrict__ src, u16* __restrict__ dst,
                                      const float* __restrict__ ctab, const float* __restrict__ stab,
                                      int s, int dstrow, int col, int rowlen, int pid) {
  const int dh = col & 127;
  const bool hih = dh >= 64;
  const u16* rowp = src + (size_t)s * rowlen;
  union { uint4 u; u16 h[8]; } X, P, O;
  X.u = *(const uint4*)(rowp + col);
  P.u = *(const uint4*)(rowp + col + (hih ? -64 : 64));
  const float* cp = ctab + pid * 128 + dh;
  const float* sp = stab + pid * 128 + dh;
#pragma unroll
  for (int j = 0; j < 8; ++j) {
    float v = bf2f(X.h[j]) * cp[j] + (hih ? bf2f(P.h[j]) : -bf2f(P.h[j])) * sp[j];
    O.h[j] = f2bf(v);
  }
  *(uint4*)(dst + (size_t)dstrow * rowlen + col) = O.u;
}
__global__ void rope_all_kernel(const u16* __restrict__ q_tmp, const u16* __restrict__ k_tmp,
                                u16* __restrict__ qa, u16* __restrict__ qb, u16* __restrict__ qf,
                                u16* __restrict__ k_bf, const float* __restrict__ q_cos,
                                const float* __restrict__ q_sin, const float* __restrict__ qc_cos,
                                const float* __restrict__ qc_sin, const float* __restrict__ k_cos,
                                const float* __restrict__ k_sin) {
  int o = blockIdx.x * blockDim.x + threadIdx.x;
  if (o < RP_N0) {
    int r = o >> 8, col = (o & 255) * 8;
    rope8(q_tmp, qa, q_cos, q_sin, r, r, col, 2048, r % CLEN);
    return;
  }
  o -= RP_N0;
  if (o < RP_N1) {
    int r = o >> 8, col = (o & 255) * 8, s = CLEN + r;
    rope8(q_tmp, qb, qc_cos, qc_sin, s, r, col, 2048, s % CLEN);
    return;
  }
  o -= RP_N1;
  if (o < RP_N2) {
    int r = o >> 8, col = (o & 255) * 8, s = 2 * CLEN + r;
    rope8(q_tmp, qf, qc_cos, qc_sin, s, r, col, 2048, CLEN - 1);
    return;
  }
  o -= RP_N2;
  if (o < RP_N3) {
    int r = o >> 6, col = (o & 63) * 8;
    rope8(k_tmp, k_bf, k_cos, k_sin, r, r, col, 512, r);
  }
}

// ---------------- fused QKV GEMM: C = h * Wqkv^T, N=3072, routed outputs ----
__global__ __launch_bounds__(256) void gemm_qkv(const u16* __restrict__ A, const u16* __restrict__ B,
                                                u16* __restrict__ q_tmp, u16* __restrict__ k_tmp,
                                                u16* __restrict__ vT) {
  __shared__ __align__(16) u16 Al[128 * 64];
  __shared__ __align__(16) u16 Bl[128 * 64];
  const int K = HID;
  const int t = threadIdx.x;
  const int lane = t & 63, wid = t >> 6;
  const int g = lane >> 4, c = lane & 15;
  const int wr = wid >> 1, wc = wid & 1;
  const int m0 = blockIdx.x * 128, n0 = blockIdx.y * 128;

  f32x4 acc[4][4];
#pragma unroll
  for (int m = 0; m < 4; ++m)
#pragma unroll
    for (int n = 0; n < 4; ++n) acc[m][n] = (f32x4){0.f, 0.f, 0.f, 0.f};

  const int srow = t >> 3;
  const int scol = (t & 7) * 8;
  for (int k0 = 0; k0 < K; k0 += 64) {
    __syncthreads();
#pragma unroll
    for (int i = 0; i < 4; ++i) {
      const int r = i * 32 + srow;
      gload_lds16(A + (size_t)(m0 + r) * K + k0 + scol, Al + i * 2048 + wid * 512);
      gload_lds16(B + (size_t)(n0 + r) * K + k0 + scol, Bl + i * 2048 + wid * 512);
    }
    __syncthreads();
#pragma unroll
    for (int kk = 0; kk < 2; ++kk) {
      bf16x8 af[4], bfr[4];
#pragma unroll
      for (int m = 0; m < 4; ++m)
        af[m] = *(const bf16x8*)(Al + (wr * 64 + m * 16 + c) * 64 + kk * 32 + g * 8);
#pragma unroll
      for (int n = 0; n < 4; ++n)
        bfr[n] = *(const bf16x8*)(Bl + (wc * 64 + n * 16 + c) * 64 + kk * 32 + g * 8);
#pragma unroll
      for (int m = 0; m < 4; ++m)
#pragma unroll
        for (int n = 0; n < 4; ++n)
          acc[m][n] = mfma16(af[m], bfr[n], acc[m][n]);
    }
  }
#pragma unroll
  for (int m = 0; m < 4; ++m)
#pragma unroll
    for (int n = 0; n < 4; ++n)
#pragma unroll
      for (int j = 0; j < 4; ++j) {
        const int row = m0 + wr * 64 + m * 16 + 4 * g + j;
        const int col = n0 + wc * 64 + n * 16 + c;
        const float v = acc[m][n][j];
        if (n0 < 2048)       q_tmp[(size_t)row * 2048 + col] = f2bf(v);
        else if (n0 < 2560)  k_tmp[(size_t)row * 512 + (col - 2048)] = f2bf(v);
        else                 vT[(size_t)(col - 2560) * SEQL + row] = f2bf(v);
      }
}

// ---------------- O-projection GEMM: f32 out -------------------------------
__global__ __launch_bounds__(256) void gemm_o(const u16* __restrict__ A, const u16* __restrict__ B,
                                              float* __restrict__ Cf) {
  __shared__ __align__(16) u16 Al[128 * 64];
  __shared__ __align__(16) u16 Bl[128 * 64];
  const int K = HID, N = HID;
  const int t = threadIdx.x;
  const int lane = t & 63, wid = t >> 6;
  const int g = lane >> 4, c = lane & 15;
  const int wr = wid >> 1, wc = wid & 1;
  const int m0 = blockIdx.x * 128, n0 = blockIdx.y * 128;

  f32x4 acc[4][4];
#pragma unroll
  for (int m = 0; m < 4; ++m)
#pragma unroll
    for (int n = 0; n < 4; ++n) acc[m][n] = (f32x4){0.f, 0.f, 0.f, 0.f};

  const int srow = t >> 3;
  const int scol = (t & 7) * 8;
  for (int k0 = 0; k0 < K; k0 += 64) {
    __syncthreads();
#pragma unroll
    for (int i = 0; i < 4; ++i) {
      const int r = i * 32 + srow;
      gload_lds16(A + (size_t)(m0 + r) * K + k0 + scol, Al + i * 2048 + wid * 512);
      gload_lds16(B + (size_t)(n0 + r) * K + k0 + scol, Bl + i * 2048 + wid * 512);
    }
    __syncthreads();
#pragma unroll
    for (int kk = 0; kk < 2; ++kk) {
      bf16x8 af[4], bfr[4];
#pragma unroll
      for (int m = 0; m < 4; ++m)
        af[m] = *(const bf16x8*)(Al + (wr * 64 + m * 16 + c) * 64 + kk * 32 + g * 8);
#pragma unroll
      for (int n = 0; n < 4; ++n)
        bfr[n] = *(const bf16x8*)(Bl + (wc * 64 + n * 16 + c) * 64 + kk * 32 + g * 8);
#pragma unroll
      for (int m = 0; m < 4; ++m)
#pragma unroll
        for (int n = 0; n < 4; ++n)
          acc[m][n] = mfma16(af[m], bfr[n], acc[m][n]);
    }
  }
#pragma unroll
  for (int m = 0; m < 4; ++m)
#pragma unroll
    for (int n = 0; n < 4; ++n)
#pragma unroll
      for (int j = 0; j < 4; ++j) {
        const int row = m0 + wr * 64 + m * 16 + 4 * g + j;
        const int col = n0 + wc * 64 + n * 16 + c;
        Cf[(size_t)row * N + col] = acc[m][n][j];
      }
}

// ---------------- partial attention: one (chunk, seg, qtile, head) ---------
// grid (13, 6, 16), block 256 (4 waves x 32 q-rows). Writes normalized O + lse.
__global__ __launch_bounds__(256) void attn_kernel(
    const u16* __restrict__ qa, const u16* __restrict__ qb, const u16* __restrict__ qf,
    const u16* __restrict__ kbf, const u16* __restrict__ vT,
    u16* __restrict__ Opart, float* __restrict__ lseout) {
  __shared__ __align__(16) u16 Klds[2][64 * 128];  // [kv][d], granule ^= row&7
  __shared__ __align__(16) u16 Vlds[2][128 * 64];  // [d][kv], granule ^= row&7
  __shared__ float albuf[4][32];

  const int y = blockIdx.y, head = blockIdx.z;
  // part tables: fulls first (heavy), then causals
  const int ctab[6] = {1, 2, 2, 0, 1, 2};
  const int stab[6] = {0, 1, 0, 0, 1, 2};
  const int ltab[6] = {1, 1, 2, 0, 0, 0};
  const int chunk = ctab[y], seg = stab[y], slot = ltab[y];
  const bool causal = (seg == chunk);
  const int qt = causal ? (12 - (int)blockIdx.x) : (int)blockIdx.x;

  const int t = threadIdx.x, wid = t >> 6, lane = t & 63;
  const int ql = lane & 31, hi = lane >> 5;
  const int kvh = head >> 2;
  const int qcb = qt * 128 + wid * 32;
  const int qpos = qcb + ql;
  const int kvbase = seg * CLEN;

  const u16* qp; int qoff;
  if (causal)                { qp = qa; qoff = 0; }
  else if (seg == chunk - 1) { qp = qb; qoff = CLEN; }
  else                       { qp = qf; qoff = 2 * CLEN; }

  bf16x8 aq[8];
  {
    const u16* qrow = qp + (size_t)(chunk * CLEN + qpos - qoff) * HID + head * HD + hi * 8;
#pragma unroll
    for (int ck = 0; ck < 8; ++ck) aq[ck] = *(const bf16x8*)(qrow + ck * 16);
  }

  float m_r = 0.f, l_r = 0.f;
  f32x16 oacc[4];
#pragma unroll
  for (int db = 0; db < 4; ++db)
#pragma unroll
    for (int r = 0; r < 16; ++r) oacc[db][r] = 0.f;

  const int ksr = t >> 4, ksc = t & 15;
  const int vsr = t >> 3, vsc = t & 7;
  const int nt = causal ? (qt * 2 + 2) : (CLEN / 64);

  auto stage = [&](int b, int kt) {
    const int kv0 = kt * 64;
#pragma unroll
    for (int i = 0; i < 4; ++i) {
      const int r = ksr + 16 * i;
      const int gs = ksc ^ (r & 7);
      gload_lds16(kbf + (size_t)(kvbase + kv0 + r) * KVD + kvh * HD + gs * 8,
                  &Klds[b][i * 2048 + wid * 512]);
    }
#pragma unroll
    for (int i = 0; i < 4; ++i) {
      const int r = vsr + 32 * i;
      const int gs = vsc ^ (r & 7);
      gload_lds16(vT + (size_t)(kvh * HD + r) * SEQL + kvbase + kv0 + gs * 8,
                  &Vlds[b][i * 2048 + wid * 512]);
    }
  };

  stage(0, 0);
  int cur = 0;
  for (int kt = 0; kt < nt; ++kt) {
    if (kt + 1 < nt) {
      stage(cur ^ 1, kt + 1);
      asm volatile("s_waitcnt vmcnt(8)" ::: "memory");
    } else {
      asm volatile("s_waitcnt vmcnt(0)" ::: "memory");
    }
    __builtin_amdgcn_s_barrier();
    const int kv0 = kt * 64;
    const u16* Kb = &Klds[cur][0];
    const u16* Vb = &Vlds[cur][0];
#pragma unroll
    for (int s = 0; s < 2; ++s) {
      if (!(causal && kv0 + 32 * s > qcb + 31)) {
        f32x16 sacc;
#pragma unroll
        for (int r = 0; r < 16; ++r) sacc[r] = 0.f;
        const int kr = 32 * s + ql;
        const int r7 = lane & 7;
#pragma unroll
        for (int ck = 0; ck < 8; ++ck) {
          bf16x8 kb = *(const bf16x8*)(Kb + kr * 128 + (((2 * ck + hi) ^ r7) * 8));
          sacc = mfma32(kb, aq[ck], sacc);
        }
        float e[16];
        float mt = -1e30f;
#pragma unroll
        for (int r = 0; r < 16; ++r) {
          const int kvp = kv0 + 32 * s + (r & 3) + 8 * (r >> 2) + 4 * hi;
          float ev = sacc[r] * SCALE;
          if (causal && kvp > qpos) ev = -1e30f;
          e[r] = ev;
          mt = fmaxf(mt, ev);
        }
        mt = fmaxf(mt, __shfl_xor(mt, 32));
        if (!__all(mt <= m_r + 8.f)) {  // rare defer-max rescale
          const float mnew = fmaxf(m_r, mt);
          const float al = __expf(m_r - mnew);
          m_r = mnew; l_r *= al;
          albuf[wid][ql] = al;
          asm volatile("s_waitcnt lgkmcnt(0)" ::: "memory");
#pragma unroll
          for (int r = 0; r < 16; ++r) {
            const float alr = albuf[wid][(r & 3) + 8 * (r >> 2) + 4 * hi];
#pragma unroll
            for (int db = 0; db < 4; ++db) oacc[db][r] *= alr;
          }
        }
        float rs = 0.f;
#pragma unroll
        for (int r = 0; r < 16; ++r) { e[r] = __expf(e[r] - m_r); rs += e[r]; }
        rs += __shfl_xor(rs, 32);
        l_r += rs;
        u32 w[8];
#pragma unroll
        for (int j = 0; j < 8; ++j) w[j] = cvtpk(e[2 * j], e[2 * j + 1]);
#pragma unroll
        for (int ks = 0; ks < 2; ++ks) {
          union { uint4 u; bf16x8 v; } pa;
          pa.u.x = w[4 * ks]; pa.u.y = w[4 * ks + 1];
          pa.u.z = w[4 * ks + 2]; pa.u.w = w[4 * ks + 3];
          const int g4a = 8 * s + 4 * ks + hi;
          const int sw = (lane & 7) << 1;
#pragma unroll
          for (int db = 0; db < 4; ++db) {
            const int vrow = 32 * db + ql;
            const uint2 v0 = *(const uint2*)(Vb + vrow * 64 + ((g4a ^ sw) * 4));
            const uint2 v1 = *(const uint2*)(Vb + vrow * 64 + (((g4a + 2) ^ sw) * 4));
            union { uint4 u; bf16x8 v; } bv;
            bv.u.x = v0.x; bv.u.y = v0.y; bv.u.z = v1.x; bv.u.w = v1.y;
            oacc[db] = mfma32(pa.v, bv.v, oacc[db]);
          }
        }
      }
    }
    __builtin_amdgcn_s_barrier();
    cur ^= 1;
  }
  // epilogue: normalized partial O (bf16) + lse
  const float linv = 1.0f / l_r;
  albuf[wid][ql] = linv;
  asm volatile("s_waitcnt lgkmcnt(0)" ::: "memory");
#pragma unroll
  for (int r = 0; r < 16; ++r) {
    const int rrow = (r & 3) + 8 * (r >> 2) + 4 * hi;
    const float li = albuf[wid][rrow];
    const size_t grow = (size_t)(chunk * CLEN + qcb + rrow);
#pragma unroll
    for (int db = 0; db < 4; ++db)
      Opart[((size_t)slot * SEQL + grow) * HID + head * HD + db * 32 + ql] = f2bf(oacc[db][r] * li);
  }
  if (hi == 0)
    lseout[((size_t)slot * NHEADS + head) * SEQL + chunk * CLEN + qcb + ql] = m_r + __logf(l_r);
}

// ---------------- merge partials (softmax over lse) ------------------------
__global__ void merge_kernel(const u16* __restrict__ Opart, const float* __restrict__ lse,
                             u16* __restrict__ amrg) {
  const int idx = blockIdx.x * blockDim.x + threadIdx.x;  // 4992*256 threads
  const int row = idx >> 8;
  const int col = (idx & 255) * 8;
  const int head = col >> 7;
  const int np = row / CLEN + 1;
  float ls[3];
  float mx = -1e30f;
  for (int i = 0; i < np; ++i) {
    ls[i] = lse[((size_t)i * NHEADS + head) * SEQL + row];
    mx = fmaxf(mx, ls[i]);
  }
  float wsum = 0.f;
  for (int i = 0; i < np; ++i) { ls[i] = __expf(ls[i] - mx); wsum += ls[i]; }
  const float inv = 1.0f / wsum;
  float acc[8];
#pragma unroll
  for (int j = 0; j < 8; ++j) acc[j] = 0.f;
  for (int i = 0; i < np; ++i) {
    union { uint4 u; u16 h[8]; } X;
    X.u = *(const uint4*)(Opart + ((size_t)i * SEQL + row) * (size_t)HID + col);
#pragma unroll
    for (int j = 0; j < 8; ++j) acc[j] += ls[i] * bf2f(X.h[j]);
  }
  union { uint4 u; u16 h[8]; } O;
#pragma unroll
  for (int j = 0; j < 8; ++j) O.h[j] = f2bf(acc[j] * inv);
  *(uint4*)(amrg + (size_t)row * 2048 + col) = O.u;
}

extern "C" void kernel_launch(void* const* d_in, const int* in_sizes, int n_in,
                              void* d_out, int out_size, void* d_ws, size_t ws_size,
                              hipStream_t stream) {
  (void)in_sizes; (void)n_in; (void)out_size; (void)ws_size;
  const float* hidden = (const float*)d_in[0];
  const float* q_cos = (const float*)d_in[2];
  const float* q_sin = (const float*)d_in[3];
  const float* qc_cos = (const float*)d_in[4];
  const float* qc_sin = (const float*)d_in[5];
  const float* k_cos = (const float*)d_in[6];
  const float* k_sin = (const float*)d_in[7];
  const float* Wq = (const float*)d_in[8];
  const float* Wk = (const float*)d_in[9];
  const float* Wv = (const float*)d_in[10];
  const float* Wo = (const float*)d_in[11];
  float* out = (float*)d_out;

  char* ws = (char*)d_ws;
  // fixed region
  u16* Wo_bf = (u16*)(ws + 0);                      //  8,388,608
  u16* qa    = (u16*)(ws + 8388608);                // 20,447,232
  u16* qb    = (u16*)(ws + 28835840);               // 13,631,488
  u16* qf    = (u16*)(ws + 42467328);               //  6,815,744
  u16* k_bf  = (u16*)(ws + 49283072);               //  5,111,808
  u16* vT    = (u16*)(ws + 54394880);               //  5,111,808
  char* BIG  = ws + 59506688;
  // BIG overlay, phase 1-3
  u16* h_bf  = (u16*)(BIG + 0);                     // 20,447,232
  u16* Wqkv  = (u16*)(BIG + 20447232);              // 12,582,912
  u16* q_tmp = (u16*)(BIG + 33030144);              // 20,447,232
  u16* k_tmp = (u16*)(BIG + 53477376);              //  5,111,808
  // BIG overlay, phase 4-5
  u16* Opart = (u16*)(BIG + 0);                     // 61,341,696 (3 slots)
  float* lse = (float*)(BIG + 61341696);            //    958,464
  u16* amrg  = qa;                                  // alias: qa dead after attn

  cvt_all_kernel<<<dim3(20224), dim3(256), 0, stream>>>(hidden, Wq, Wk, Wv, Wo, h_bf, Wqkv, Wo_bf);
  gemm_qkv<<<dim3(SEQL / 128, 24), 256, 0, stream>>>(h_bf, Wqkv, q_tmp, k_tmp, vT);
  rope_all_kernel<<<dim3(11232), dim3(256), 0, stream>>>(q_tmp, k_tmp, qa, qb, qf, k_bf,
                                                         q_cos, q_sin, qc_cos, qc_sin, k_cos, k_sin);
  attn_kernel<<<dim3(13, 6, NHEADS), 256, 0, stream>>>(qa, qb, qf, k_bf, vT, Opart, lse);
  merge_kernel<<<dim3(SEQL), dim3(256), 0, stream>>>(Opart, lse, amrg);
  gemm_o<<<dim3(SEQL / 128, HID / 128), 256, 0, stream>>>(amrg, Wo_bf, out);
}

// Round 5
// 554.507 us; speedup vs baseline: 1.5393x; 1.0448x over previous
//
#include <hip/hip_runtime.h>

typedef unsigned short u16;
typedef unsigned int u32;
typedef __attribute__((ext_vector_type(8))) __bf16 bf16x8;
typedef __attribute__((ext_vector_type(4))) float f32x4;
typedef __attribute__((ext_vector_type(16))) float f32x16;

#define CLEN 1664
#define SEQL 4992
#define NHEADS 16
#define HD 128
#define HID 2048
#define KVD 512
#define SCALE 0.08838834764831845f
#define NPARTS 672

__device__ __forceinline__ u16 f2bf(float f) {
  union { float f; u32 u; } v; v.f = f;
  u32 u = v.u;
  return (u16)((u + 0x7FFFu + ((u >> 16) & 1u)) >> 16);
}
__device__ __forceinline__ float bf2f(u16 h) {
  union { u32 u; float f; } v; v.u = (u32)h << 16;
  return v.f;
}
__device__ __forceinline__ f32x4 mfma16(bf16x8 a, bf16x8 b, f32x4 c) {
  return __builtin_amdgcn_mfma_f32_16x16x32_bf16(a, b, c, 0, 0, 0);
}
__device__ __forceinline__ f32x16 mfma32(bf16x8 a, bf16x8 b, f32x16 c) {
  return __builtin_amdgcn_mfma_f32_32x32x16_bf16(a, b, c, 0, 0, 0);
}
__device__ __forceinline__ u32 cvtpk(float lo, float hi) {
  u32 r;
  asm("v_cvt_pk_bf16_f32 %0, %1, %2" : "=v"(r) : "v"(lo), "v"(hi));
  return r;
}
__device__ __forceinline__ void gload_lds16(const u16* g, u16* l) {
  __builtin_amdgcn_global_load_lds((const __attribute__((address_space(1))) void*)g,
                                   (__attribute__((address_space(3))) void*)l, 16, 0, 0);
}

// ---------------- fused f32 -> bf16 convert (5 regions, 1 launch) ----------
#define CVT_Q0 2555904   // hidden  (10223616/4)
#define CVT_Q1 1048576   // Wq
#define CVT_Q2 262144    // Wk
#define CVT_Q3 262144    // Wv
#define CVT_Q4 1048576   // Wo
__device__ __forceinline__ void cvt4(const float* s, u16* d, int q) {
  float4 v = *(const float4*)(s + (size_t)q * 4);
  uint2 p;
  p.x = (u32)f2bf(v.x) | ((u32)f2bf(v.y) << 16);
  p.y = (u32)f2bf(v.z) | ((u32)f2bf(v.w) << 16);
  *(uint2*)(d + (size_t)q * 4) = p;
}
__global__ void cvt_all_kernel(const float* __restrict__ hidden, const float* __restrict__ Wq,
                               const float* __restrict__ Wk, const float* __restrict__ Wv,
                               const float* __restrict__ Wo, u16* __restrict__ h_bf,
                               u16* __restrict__ Wqkv, u16* __restrict__ Wo_bf,
                               u32* __restrict__ cnt) {
  int q = blockIdx.x * blockDim.x + threadIdx.x;
  if (q == 0) *cnt = 0;   // reset attention work-queue counter every launch
  if (q < CVT_Q0) { cvt4(hidden, h_bf, q); return; }
  q -= CVT_Q0;
  if (q < CVT_Q1) { cvt4(Wq, Wqkv, q); return; }
  q -= CVT_Q1;
  if (q < CVT_Q2) { cvt4(Wk, Wqkv + 2048 * 2048, q); return; }
  q -= CVT_Q2;
  if (q < CVT_Q3) { cvt4(Wv, Wqkv + 2560 * 2048, q); return; }
  q -= CVT_Q3;
  if (q < CVT_Q4) cvt4(Wo, Wo_bf, q);
}

// ---------------- fused RoPE (4 regions, 1 launch); Q paths pre-scaled -----
#define RP_N0 1277952  // qa : 4992*256
#define RP_N1 851968   // qb : 3328*256
#define RP_N2 425984   // qf : 1664*256
#define RP_N3 319488   // k  : 4992*64
__device__ __forceinline__ void rope8(const u16* __restrict__ src, u16* __restrict__ dst,
                                      const float* __restrict__ ctab, const float* __restrict__ stab,
                                      int s, int dstrow, int col, int rowlen, int pid, float scl) {
  const int dh = col & 127;
  const bool hih = dh >= 64;
  const u16* rowp = src + (size_t)s * rowlen;
  union { uint4 u; u16 h[8]; } X, P, O;
  X.u = *(const uint4*)(rowp + col);
  P.u = *(const uint4*)(rowp + col + (hih ? -64 : 64));
  const float* cp = ctab + pid * 128 + dh;
  const float* sp = stab + pid * 128 + dh;
#pragma unroll
  for (int j = 0; j < 8; ++j) {
    float v = bf2f(X.h[j]) * cp[j] + (hih ? bf2f(P.h[j]) : -bf2f(P.h[j])) * sp[j];
    O.h[j] = f2bf(v * scl);
  }
  *(uint4*)(dst + (size_t)dstrow * rowlen + col) = O.u;
}
__global__ void rope_all_kernel(const u16* __restrict__ q_tmp, const u16* __restrict__ k_tmp,
                                u16* __restrict__ qa, u16* __restrict__ qb, u16* __restrict__ qf,
                                u16* __restrict__ k_bf, const float* __restrict__ q_cos,
                                const float* __restrict__ q_sin, const float* __restrict__ qc_cos,
                                const float* __restrict__ qc_sin, const float* __restrict__ k_cos,
                                const float* __restrict__ k_sin) {
  int o = blockIdx.x * blockDim.x + threadIdx.x;
  if (o < RP_N0) {
    int r = o >> 8, col = (o & 255) * 8;
    rope8(q_tmp, qa, q_cos, q_sin, r, r, col, 2048, r % CLEN, SCALE);
    return;
  }
  o -= RP_N0;
  if (o < RP_N1) {
    int r = o >> 8, col = (o & 255) * 8, s = CLEN + r;
    rope8(q_tmp, qb, qc_cos, qc_sin, s, r, col, 2048, s % CLEN, SCALE);
    return;
  }
  o -= RP_N1;
  if (o < RP_N2) {
    int r = o >> 8, col = (o & 255) * 8, s = 2 * CLEN + r;
    rope8(q_tmp, qf, qc_cos, qc_sin, s, r, col, 2048, CLEN - 1, SCALE);
    return;
  }
  o -= RP_N2;
  if (o < RP_N3) {
    int r = o >> 6, col = (o & 63) * 8;
    rope8(k_tmp, k_bf, k_cos, k_sin, r, r, col, 512, r, 1.0f);
  }
}

// ---------------- fused QKV GEMM: C = h * Wqkv^T, N=3072, routed outputs ----
__global__ __launch_bounds__(256) void gemm_qkv(const u16* __restrict__ A, const u16* __restrict__ B,
                                                u16* __restrict__ q_tmp, u16* __restrict__ k_tmp,
                                                u16* __restrict__ vT) {
  __shared__ __align__(16) u16 Al[128 * 64];
  __shared__ __align__(16) u16 Bl[128 * 64];
  const int K = HID;
  const int t = threadIdx.x;
  const int lane = t & 63, wid = t >> 6;
  const int g = lane >> 4, c = lane & 15;
  const int wr = wid >> 1, wc = wid & 1;
  const int m0 = blockIdx.x * 128, n0 = blockIdx.y * 128;

  f32x4 acc[4][4];
#pragma unroll
  for (int m = 0; m < 4; ++m)
#pragma unroll
    for (int n = 0; n < 4; ++n) acc[m][n] = (f32x4){0.f, 0.f, 0.f, 0.f};

  const int srow = t >> 3;
  const int scol = (t & 7) * 8;
  for (int k0 = 0; k0 < K; k0 += 64) {
    __syncthreads();
#pragma unroll
    for (int i = 0; i < 4; ++i) {
      const int r = i * 32 + srow;
      gload_lds16(A + (size_t)(m0 + r) * K + k0 + scol, Al + i * 2048 + wid * 512);
      gload_lds16(B + (size_t)(n0 + r) * K + k0 + scol, Bl + i * 2048 + wid * 512);
    }
    __syncthreads();
#pragma unroll
    for (int kk = 0; kk < 2; ++kk) {
      bf16x8 af[4], bfr[4];
#pragma unroll
      for (int m = 0; m < 4; ++m)
        af[m] = *(const bf16x8*)(Al + (wr * 64 + m * 16 + c) * 64 + kk * 32 + g * 8);
#pragma unroll
      for (int n = 0; n < 4; ++n)
        bfr[n] = *(const bf16x8*)(Bl + (wc * 64 + n * 16 + c) * 64 + kk * 32 + g * 8);
#pragma unroll
      for (int m = 0; m < 4; ++m)
#pragma unroll
        for (int n = 0; n < 4; ++n)
          acc[m][n] = mfma16(af[m], bfr[n], acc[m][n]);
    }
  }
#pragma unroll
  for (int m = 0; m < 4; ++m)
#pragma unroll
    for (int n = 0; n < 4; ++n)
#pragma unroll
      for (int j = 0; j < 4; ++j) {
        const int row = m0 + wr * 64 + m * 16 + 4 * g + j;
        const int col = n0 + wc * 64 + n * 16 + c;
        const float v = acc[m][n][j];
        if (n0 < 2048)       q_tmp[(size_t)row * 2048 + col] = f2bf(v);
        else if (n0 < 2560)  k_tmp[(size_t)row * 512 + (col - 2048)] = f2bf(v);
        else                 vT[(size_t)(col - 2560) * SEQL + row] = f2bf(v);
      }
}

// ---------------- O-projection GEMM: f32 out -------------------------------
__global__ __launch_bounds__(256) void gemm_o(const u16* __restrict__ A, const u16* __restrict__ B,
                                              float* __restrict__ Cf) {
  __shared__ __align__(16) u16 Al[128 * 64];
  __shared__ __align__(16) u16 Bl[128 * 64];
  const int K = HID, N = HID;
  const int t = threadIdx.x;
  const int lane = t & 63, wid = t >> 6;
  const int g = lane >> 4, c = lane & 15;
  const int wr = wid >> 1, wc = wid & 1;
  const int m0 = blockIdx.x * 128, n0 = blockIdx.y * 128;

  f32x4 acc[4][4];
#pragma unroll
  for (int m = 0; m < 4; ++m)
#pragma unroll
    for (int n = 0; n < 4; ++n) acc[m][n] = (f32x4){0.f, 0.f, 0.f, 0.f};

  const int srow = t >> 3;
  const int scol = (t & 7) * 8;
  for (int k0 = 0; k0 < K; k0 += 64) {
    __syncthreads();
#pragma unroll
    for (int i = 0; i < 4; ++i) {
      const int r = i * 32 + srow;
      gload_lds16(A + (size_t)(m0 + r) * K + k0 + scol, Al + i * 2048 + wid * 512);
      gload_lds16(B + (size_t)(n0 + r) * K + k0 + scol, Bl + i * 2048 + wid * 512);
    }
    __syncthreads();
#pragma unroll
    for (int kk = 0; kk < 2; ++kk) {
      bf16x8 af[4], bfr[4];
#pragma unroll
      for (int m = 0; m < 4; ++m)
        af[m] = *(const bf16x8*)(Al + (wr * 64 + m * 16 + c) * 64 + kk * 32 + g * 8);
#pragma unroll
      for (int n = 0; n < 4; ++n)
        bfr[n] = *(const bf16x8*)(Bl + (wc * 64 + n * 16 + c) * 64 + kk * 32 + g * 8);
#pragma unroll
      for (int m = 0; m < 4; ++m)
#pragma unroll
        for (int n = 0; n < 4; ++n)
          acc[m][n] = mfma16(af[m], bfr[n], acc[m][n]);
    }
  }
#pragma unroll
  for (int m = 0; m < 4; ++m)
#pragma unroll
    for (int n = 0; n < 4; ++n)
#pragma unroll
      for (int j = 0; j < 4; ++j) {
        const int row = m0 + wr * 64 + m * 16 + 4 * g + j;
        const int col = n0 + wc * 64 + n * 16 + c;
        Cf[(size_t)row * N + col] = acc[m][n][j];
      }
}

// ---------------- persistent partial-attention kernel ----------------------
// 512 blocks x 512 threads (8 waves, 256 q-rows/block). Parts claimed from a
// global atomic queue in descending-size (LPT) order. 3 merge slots as before.
__global__ __launch_bounds__(512, 4) void attn_kernel(
    const u16* __restrict__ qa, const u16* __restrict__ qbuf, const u16* __restrict__ qf,
    const u16* __restrict__ kbf, const u16* __restrict__ vT,
    u16* __restrict__ Opart, float* __restrict__ lseout, u32* __restrict__ cnt) {
  __shared__ __align__(16) u16 Klds[2][64 * 128];  // [kv][d], granule ^= row&7
  __shared__ __align__(16) u16 Vlds[2][128 * 64];  // [d][kv], granule ^= row&7
  __shared__ float albuf[8][32];
  __shared__ int wsh;

  const int t = threadIdx.x, wid = t >> 6, lane = t & 63;
  const int ql = lane & 31, hi = lane >> 5;
  const int ksr = t >> 4, ksc = t & 15;  // K staging: row ksr+32i
  const int vsr = t >> 3, vsc = t & 7;   // V staging: row vsr+64i

  for (;;) {
    __syncthreads();
    if (t == 0) wsh = (int)atomicAdd(cnt, 1u);
    __syncthreads();
    const int w = wsh;
    if (w >= NPARTS) break;

    // ---- decode part: rank sorted by descending tile count ----
    const int head = w & 15, rk = w >> 4;
    int chunk, seg, qb;
    if (rk < 21) {            // full parts: (1,0),(2,0),(2,1) x qb 0..6, 26 tiles
      const int part = rk / 7; qb = rk % 7;
      chunk = (part == 0) ? 1 : 2;
      seg = (part == 2) ? 1 : 0;
    } else if (rk < 24) {     // causal qb=6 (26 tiles)
      chunk = rk - 21; seg = chunk; qb = 6;
    } else {                  // causal qb 5..0 descending (24..4 tiles)
      const int g2 = rk - 24;
      qb = 5 - g2 / 3; chunk = g2 % 3; seg = chunk;
    }
    const bool causal = (seg == chunk);
    const int nt = causal ? ((qb == 6) ? 26 : (4 * qb + 4)) : 26;
    const int slot = causal ? 0 : ((chunk - seg == 1) ? 1 : 2);
    const int kvh = head >> 2;
    const int kvbase = seg * CLEN;
    const int qcb = qb * 256 + wid * 32;
    const int qpos = qcb + ql;
    const bool wact = qcb < CLEN;   // qb==6 upper waves idle

    const u16* qp; int qoff;
    if (causal)                { qp = qa;   qoff = 0; }
    else if (chunk - seg == 1) { qp = qbuf; qoff = CLEN; }
    else                       { qp = qf;   qoff = 2 * CLEN; }

    bf16x8 aq[8];
    {
      const int qrow = wact ? (chunk * CLEN + qpos - qoff) : 0;
      const u16* qptr = qp + (size_t)qrow * HID + head * HD + hi * 8;
#pragma unroll
      for (int ck = 0; ck < 8; ++ck) aq[ck] = *(const bf16x8*)(qptr + ck * 16);
    }

    float l_r = 0.f;
    f32x16 oacc[4];
#pragma unroll
    for (int db = 0; db < 4; ++db)
#pragma unroll
      for (int r = 0; r < 16; ++r) oacc[db][r] = 0.f;

    auto stage = [&](int b, int kt) {
      const int kv0 = kt * 64;
#pragma unroll
      for (int i = 0; i < 2; ++i) {
        const int rr = ksr + 32 * i;
        const int gs = ksc ^ (rr & 7);
        gload_lds16(kbf + (size_t)(kvbase + kv0 + rr) * KVD + kvh * HD + gs * 8,
                    &Klds[b][i * 4096 + wid * 512]);
      }
#pragma unroll
      for (int i = 0; i < 2; ++i) {
        const int rr = vsr + 64 * i;
        const int gs = vsc ^ (rr & 7);
        gload_lds16(vT + (size_t)(kvh * HD + rr) * SEQL + kvbase + kv0 + gs * 8,
                    &Vlds[b][i * 4096 + wid * 512]);
      }
    };

    stage(0, 0);
    int cur = 0;
    for (int kt = 0; kt < nt; ++kt) {
      if (kt + 1 < nt) {
        stage(cur ^ 1, kt + 1);
        asm volatile("s_waitcnt vmcnt(4)" ::: "memory");
      } else {
        asm volatile("s_waitcnt vmcnt(0)" ::: "memory");
      }
      __builtin_amdgcn_s_barrier();
      const int kv0 = kt * 64;
      const u16* Kb = &Klds[cur][0];
      const u16* Vb = &Vlds[cur][0];
#pragma unroll
      for (int s = 0; s < 2; ++s) {
        if (wact && !(causal && kv0 + 32 * s > qcb + 31)) {
          // ---- QK^T (swapped): lane owns q=ql, 16 kv rows ----
          f32x16 sacc;
#pragma unroll
          for (int r = 0; r < 16; ++r) sacc[r] = 0.f;
          const int kr = 32 * s + ql;
          const int r7 = lane & 7;
#pragma unroll
          for (int ck = 0; ck < 8; ++ck) {
            bf16x8 kb = *(const bf16x8*)(Kb + kr * 128 + (((2 * ck + hi) ^ r7) * 8));
            sacc = mfma32(kb, aq[ck], sacc);
          }
          // ---- softmax, fixed m=0 (scores pre-scaled, |s| << 1) ----
          float e[16];
          float rs = 0.f;
#pragma unroll
          for (int r = 0; r < 16; ++r) {
            const int kvp = kv0 + 32 * s + (r & 3) + 8 * (r >> 2) + 4 * hi;
            float ev = sacc[r];
            if (causal && kvp > qpos) ev = -1e30f;
            e[r] = __expf(ev);
            rs += e[r];
          }
          rs += __shfl_xor(rs, 32);
          l_r += rs;
          u32 wp[8];
#pragma unroll
          for (int j = 0; j < 8; ++j) wp[j] = cvtpk(e[2 * j], e[2 * j + 1]);
#pragma unroll
          for (int ks = 0; ks < 2; ++ks) {
            union { uint4 u; bf16x8 v; } pa;
            pa.u.x = wp[4 * ks]; pa.u.y = wp[4 * ks + 1];
            pa.u.z = wp[4 * ks + 2]; pa.u.w = wp[4 * ks + 3];
            const int g4a = 8 * s + 4 * ks + hi;
            const int sw = (lane & 7) << 1;
#pragma unroll
            for (int db = 0; db < 4; ++db) {
              const int vrow = 32 * db + ql;
              const uint2 v0 = *(const uint2*)(Vb + vrow * 64 + ((g4a ^ sw) * 4));
              const uint2 v1 = *(const uint2*)(Vb + vrow * 64 + (((g4a + 2) ^ sw) * 4));
              union { uint4 u; bf16x8 v; } bv;
              bv.u.x = v0.x; bv.u.y = v0.y; bv.u.z = v1.x; bv.u.w = v1.y;
              oacc[db] = mfma32(pa.v, bv.v, oacc[db]);
            }
          }
        }
      }
      __builtin_amdgcn_s_barrier();
      cur ^= 1;
    }
    // ---- epilogue: normalized partial O (bf16) + lse ----
    if (wact) {
      const float linv = 1.0f / l_r;
      albuf[wid][ql] = linv;
      asm volatile("s_waitcnt lgkmcnt(0)" ::: "memory");
#pragma unroll
      for (int r = 0; r < 16; ++r) {
        const int rrow = (r & 3) + 8 * (r >> 2) + 4 * hi;
        const float li = albuf[wid][rrow];
        const size_t grow = (size_t)(chunk * CLEN + qcb + rrow);
#pragma unroll
        for (int db = 0; db < 4; ++db)
          Opart[((size_t)slot * SEQL + grow) * HID + head * HD + db * 32 + ql] =
              f2bf(oacc[db][r] * li);
      }
      if (hi == 0)
        lseout[((size_t)slot * NHEADS + head) * SEQL + chunk * CLEN + qcb + ql] = __logf(l_r);
    }
  }
}

// ---------------- merge partials (softmax over lse) ------------------------
__global__ void merge_kernel(const u16* __restrict__ Opart, const float* __restrict__ lse,
                             u16* __restrict__ amrg) {
  const int idx = blockIdx.x * blockDim.x + threadIdx.x;  // 4992*256 threads
  const int row = idx >> 8;
  const int col = (idx & 255) * 8;
  const int head = col >> 7;
  const int np = row / CLEN + 1;
  float ls[3];
  float mx = -1e30f;
  for (int i = 0; i < np; ++i) {
    ls[i] = lse[((size_t)i * NHEADS + head) * SEQL + row];
    mx = fmaxf(mx, ls[i]);
  }
  float wsum = 0.f;
  for (int i = 0; i < np; ++i) { ls[i] = __expf(ls[i] - mx); wsum += ls[i]; }
  const float inv = 1.0f / wsum;
  float acc[8];
#pragma unroll
  for (int j = 0; j < 8; ++j) acc[j] = 0.f;
  for (int i = 0; i < np; ++i) {
    union { uint4 u; u16 h[8]; } X;
    X.u = *(const uint4*)(Opart + ((size_t)i * SEQL + row) * (size_t)HID + col);
#pragma unroll
    for (int j = 0; j < 8; ++j) acc[j] += ls[i] * bf2f(X.h[j]);
  }
  union { uint4 u; u16 h[8]; } O;
#pragma unroll
  for (int j = 0; j < 8; ++j) O.h[j] = f2bf(acc[j] * inv);
  *(uint4*)(amrg + (size_t)row * 2048 + col) = O.u;
}

extern "C" void kernel_launch(void* const* d_in, const int* in_sizes, int n_in,
                              void* d_out, int out_size, void* d_ws, size_t ws_size,
                              hipStream_t stream) {
  (void)in_sizes; (void)n_in; (void)out_size; (void)ws_size;
  const float* hidden = (const float*)d_in[0];
  const float* q_cos = (const float*)d_in[2];
  const float* q_sin = (const float*)d_in[3];
  const float* qc_cos = (const float*)d_in[4];
  const float* qc_sin = (const float*)d_in[5];
  const float* k_cos = (const float*)d_in[6];
  const float* k_sin = (const float*)d_in[7];
  const float* Wq = (const float*)d_in[8];
  const float* Wk = (const float*)d_in[9];
  const float* Wv = (const float*)d_in[10];
  const float* Wo = (const float*)d_in[11];
  float* out = (float*)d_out;

  char* ws = (char*)d_ws;
  // fixed region
  u16* Wo_bf = (u16*)(ws + 0);                      //  8,388,608
  u16* qa    = (u16*)(ws + 8388608);                // 20,447,232
  u16* qb    = (u16*)(ws + 28835840);               // 13,631,488
  u16* qf    = (u16*)(ws + 42467328);               //  6,815,744
  u16* k_bf  = (u16*)(ws + 49283072);               //  5,111,808
  u16* vT    = (u16*)(ws + 54394880);               //  5,111,808
  char* BIG  = ws + 59506688;
  // BIG overlay, phase 1-3
  u16* h_bf  = (u16*)(BIG + 0);                     // 20,447,232
  u16* Wqkv  = (u16*)(BIG + 20447232);              // 12,582,912
  u16* q_tmp = (u16*)(BIG + 33030144);              // 20,447,232
  u16* k_tmp = (u16*)(BIG + 53477376);              //  5,111,808
  // BIG overlay, phase 4-5
  u16* Opart = (u16*)(BIG + 0);                     // 61,341,696 (3 slots)
  float* lse = (float*)(BIG + 61341696);            //    958,464
  u32* cnt   = (u32*)(BIG + 61341696 + 958464);     //        256
  u16* amrg  = qa;                                  // alias: qa dead after attn

  cvt_all_kernel<<<dim3(20224), dim3(256), 0, stream>>>(hidden, Wq, Wk, Wv, Wo, h_bf, Wqkv, Wo_bf, cnt);
  gemm_qkv<<<dim3(SEQL / 128, 24), 256, 0, stream>>>(h_bf, Wqkv, q_tmp, k_tmp, vT);
  rope_all_kernel<<<dim3(11232), dim3(256), 0, stream>>>(q_tmp, k_tmp, qa, qb, qf, k_bf,
                                                         q_cos, q_sin, qc_cos, qc_sin, k_cos, k_sin);
  attn_kernel<<<dim3(512), dim3(512), 0, stream>>>(qa, qb, qf, k_bf, vT, Opart, lse, cnt);
  merge_kernel<<<dim3(SEQL), dim3(256), 0, stream>>>(Opart, lse, amrg);
  gemm_o<<<dim3(SEQL / 128, HID / 128), 256, 0, stream>>>(amrg, Wo_bf, out);
}